// Round 3
// baseline (829.758 us; speedup 1.0000x reference)
//
#include <hip/hip_runtime.h>
#include <hip/hip_bf16.h>
#include <math.h>

// ---------------------------------------------------------------------------
// GINE model: 3x (GINEConv + BN + ReLU) -> global mean pool -> MLP -> sigmoid
// Round 3: CSR-ordered edge features (streaming), bf16 node features for the
// gather, 8x4-register-tiled node GEMM, fused pool+head.
// ---------------------------------------------------------------------------

static __device__ __forceinline__ float bf2f(unsigned short u) {
    union { unsigned int u32; float f; } c; c.u32 = ((unsigned int)u) << 16; return c.f;
}
static __device__ __forceinline__ unsigned short f2bf(float f) {
    union { float f; unsigned int u; } c; c.f = f;
    unsigned int lsb = (c.u >> 16) & 1u;
    c.u += 0x7fffu + lsb;
    return (unsigned short)(c.u >> 16);
}

__global__ void k_zero_i(int* __restrict__ p, int n) {
    int i = blockIdx.x * blockDim.x + threadIdx.x;
    int st = gridDim.x * blockDim.x;
    for (; i < n; i += st) p[i] = 0;
}

__global__ void k_copy_i(const int* __restrict__ s, int* __restrict__ d, int n) {
    int i = blockIdx.x * blockDim.x + threadIdx.x;
    int st = gridDim.x * blockDim.x;
    for (; i < n; i += st) d[i] = s[i];
}

// transpose W[J][K] -> Wt[K][J]
__global__ void k_transpose(const float* __restrict__ W, float* __restrict__ Wt, int J, int K) {
    int idx = blockIdx.x * blockDim.x + threadIdx.x;
    if (idx < J * K) {
        int j = idx / K, k = idx % K;
        Wt[k * J + j] = W[idx];
    }
}

__global__ void k_hist(const int* __restrict__ v, int* __restrict__ cnt, int n) {
    int i = blockIdx.x * blockDim.x + threadIdx.x;
    int st = gridDim.x * blockDim.x;
    for (; i < n; i += st) atomicAdd(&cnt[v[i]], 1);
}

// single-block exclusive scan, out has n+1 entries (out[n] = total)
__global__ __launch_bounds__(1024) void k_scan(const int* __restrict__ in,
                                               int* __restrict__ out, int n) {
    __shared__ int wsum[16];
    __shared__ int carry_s;
    const int tid = threadIdx.x;
    const int lane = tid & 63, wv = tid >> 6;
    if (tid == 0) carry_s = 0;
    __syncthreads();
    for (int base = 0; base < n; base += 1024) {
        int idx = base + tid;
        int v = (idx < n) ? in[idx] : 0;
        int s = v;
#pragma unroll
        for (int off = 1; off < 64; off <<= 1) {
            int t = __shfl_up(s, off);
            if (lane >= off) s += t;
        }
        if (lane == 63) wsum[wv] = s;
        __syncthreads();
        int woff = 0;
        for (int i = 0; i < wv; ++i) woff += wsum[i];
        int carry = carry_s;
        if (idx < n) out[idx] = carry + woff + s - v;
        __syncthreads();
        if (tid == 1023) carry_s = carry + woff + s;
        __syncthreads();
    }
    if (tid == 0) out[n] = carry_s;
}

// bucket edges by dst
__global__ void k_scatter(const int* __restrict__ ei, int E, int* __restrict__ cursor,
                          int* __restrict__ eid_s, int* __restrict__ esrc_s) {
    int i = blockIdx.x * blockDim.x + threadIdx.x;
    int st = gridDim.x * blockDim.x;
    for (; i < E; i += st) {
        int d = ei[E + i];
        int pos = atomicAdd(&cursor[d], 1);
        eid_s[pos] = i;
        esrc_s[pos] = ei[i];
    }
}

// ea_s[pos] = ea[eid_s[pos]]  (float4 granules; 8 per 32-f row)
__global__ void k_permute_ea(const float* __restrict__ ea, const int* __restrict__ eid_s,
                             float* __restrict__ ea_s, int E) {
    int i = blockIdx.x * blockDim.x + threadIdx.x;
    int st = gridDim.x * blockDim.x;
    const int n4 = E * 8;
    float4* d4 = (float4*)ea_s;
    for (; i < n4; i += st) {
        int pos = i >> 3, q = i & 7;
        int e = eid_s[pos];
        d4[i] = ((const float4*)(ea + (size_t)e * 32))[q];
    }
}

// Layer-1 gather (d=64): one wave per node; lane owns channel `lane`.
__global__ __launch_bounds__(256) void k_gather64(
    const float* __restrict__ x, const int* __restrict__ rowptr,
    const int* __restrict__ esrc_s, const float* __restrict__ ea_s,
    const float* __restrict__ we, const float* __restrict__ be,
    float* __restrict__ aggr, int N)
{
    const int lane = threadIdx.x & 63;
    const int wv = threadIdx.x >> 6;
    float w[32];
    const float4* wr = (const float4*)(we + lane * 32);
#pragma unroll
    for (int q = 0; q < 8; ++q) {
        float4 t = wr[q];
        w[4*q] = t.x; w[4*q+1] = t.y; w[4*q+2] = t.z; w[4*q+3] = t.w;
    }
    const float bias = be[lane];
    for (int node = blockIdx.x * 4 + wv; node < N; node += gridDim.x * 4) {
        int beg = rowptr[node], end = rowptr[node + 1];
        float acc = x[(size_t)node * 64 + lane];
        int sn = (beg < end) ? esrc_s[beg] : 0;
        for (int idx = beg; idx < end; ++idx) {
            int s = __builtin_amdgcn_readfirstlane(sn);
            if (idx + 1 < end) sn = esrc_s[idx + 1];
            const float4* ea4 = (const float4*)(ea_s + (size_t)idx * 32);
            float dot = bias;
#pragma unroll
            for (int q = 0; q < 8; ++q) {
                float4 t = ea4[q];
                dot += t.x * w[4*q] + t.y * w[4*q+1] + t.z * w[4*q+2] + t.w * w[4*q+3];
            }
            acc += fmaxf(x[(size_t)s * 64 + lane] + dot, 0.0f);
        }
        aggr[(size_t)node * 64 + lane] = acc;
    }
}

// Layers 2/3 gather (d=256): one block per node (grid-stride); thread owns channel.
// h is bf16; ea_s streamed in CSR order.
__global__ __launch_bounds__(256) void k_gather256(
    const unsigned short* __restrict__ h, const int* __restrict__ rowptr,
    const int* __restrict__ esrc_s, const float* __restrict__ ea_s,
    const float* __restrict__ we, const float* __restrict__ be,
    float* __restrict__ aggr, int N)
{
    const int c = threadIdx.x;
    float w[32];
    const float4* wr = (const float4*)(we + c * 32);
#pragma unroll
    for (int q = 0; q < 8; ++q) {
        float4 t = wr[q];
        w[4*q] = t.x; w[4*q+1] = t.y; w[4*q+2] = t.z; w[4*q+3] = t.w;
    }
    const float bias = be[c];
    for (int n = blockIdx.x; n < N; n += gridDim.x) {
        int beg = rowptr[n], end = rowptr[n + 1];
        float acc = bf2f(h[(size_t)n * 256 + c]);
        int sn = (beg < end) ? esrc_s[beg] : 0;
        for (int idx = beg; idx < end; ++idx) {
            int s = __builtin_amdgcn_readfirstlane(sn);
            if (idx + 1 < end) sn = esrc_s[idx + 1];
            const float4* ea4 = (const float4*)(ea_s + (size_t)idx * 32);
            float dot = bias;
#pragma unroll
            for (int q = 0; q < 8; ++q) {
                float4 t = ea4[q];
                dot += t.x * w[4*q] + t.y * w[4*q+1] + t.z * w[4*q+2] + t.w * w[4*q+3];
            }
            acc += fmaxf(bf2f(h[(size_t)s * 256 + c]) + dot, 0.0f);
        }
        aggr[(size_t)n * 256 + c] = acc;
    }
}

// Node GEMM + BN + ReLU -> bf16. Block: 256 thr, 32 rows x 256 cols.
// Thread (grp=tid>>6, lane=tid&63) owns rows grp*8..+8, cols lane+64*j.
template<int K>
__global__ __launch_bounds__(256) void k_node(
    const float* __restrict__ A, const float* __restrict__ Wt,
    const float* __restrict__ bnb, const float* __restrict__ g,
    const float* __restrict__ b, const float* __restrict__ rm,
    const float* __restrict__ rv, unsigned short* __restrict__ out, int N)
{
    __shared__ float As[32 * K];
    const int tid = threadIdx.x;
    const int lane = tid & 63;
    const int grp = tid >> 6;
    const int row0 = blockIdx.x * 32;
    const int nrows = min(32, N - row0);
    const int r0 = grp * 8;

    if (nrows == 32) {
        const float4* Ag = (const float4*)(A + (size_t)row0 * K);
        float4* As4 = (float4*)As;
        for (int i = tid; i < 32 * K / 4; i += 256) As4[i] = Ag[i];
    } else {
        for (int i = tid; i < nrows * K; i += 256) As[i] = A[(size_t)row0 * K + i];
    }
    __syncthreads();

    float acc[8][4];
#pragma unroll
    for (int i = 0; i < 8; ++i)
#pragma unroll
        for (int j = 0; j < 4; ++j) acc[i][j] = 0.0f;

    for (int k = 0; k < K; k += 4) {
        float wreg[4][4];
#pragma unroll
        for (int kk = 0; kk < 4; ++kk)
#pragma unroll
            for (int j = 0; j < 4; ++j)
                wreg[kk][j] = Wt[(k + kk) * 256 + lane + 64 * j];
#pragma unroll
        for (int i = 0; i < 8; ++i) {
            float4 a = *(const float4*)&As[(r0 + i) * K + k];
#pragma unroll
            for (int j = 0; j < 4; ++j)
                acc[i][j] += a.x * wreg[0][j] + a.y * wreg[1][j]
                           + a.z * wreg[2][j] + a.w * wreg[3][j];
        }
    }

    float bias[4], scale[4], shift[4];
#pragma unroll
    for (int j = 0; j < 4; ++j) {
        int cc = lane + 64 * j;
        bias[j] = bnb[cc];
        scale[j] = g[cc] * rsqrtf(rv[cc] + 1e-5f);
        shift[j] = b[cc] - rm[cc] * scale[j];
    }
#pragma unroll
    for (int i = 0; i < 8; ++i) {
        int row = row0 + r0 + i;
        if (row < N) {
#pragma unroll
            for (int j = 0; j < 4; ++j) {
                float v = (acc[i][j] + bias[j]) * scale[j] + shift[j];
                out[(size_t)row * 256 + lane + 64 * j] = f2bf(fmaxf(v, 0.0f));
            }
        }
    }
}

// Fused global-mean-pool + MLP head (h in bf16).
__global__ __launch_bounds__(256) void k_pool_head(
    const unsigned short* __restrict__ h, const int* __restrict__ gptr,
    const float* __restrict__ w4t, const float* __restrict__ b4,
    const float* __restrict__ w5, const float* __restrict__ b5,
    float* __restrict__ out)
{
    __shared__ float pl[256];
    __shared__ float zs[128];
    const int g = blockIdx.x;
    const int tid = threadIdx.x;
    int beg = gptr[g], end = gptr[g + 1];
    float acc = 0.0f;
    for (int r = beg; r < end; ++r) acc += bf2f(h[(size_t)r * 256 + tid]);
    float cnt = (float)(end - beg);
    pl[tid] = acc / fmaxf(cnt, 1.0f);
    __syncthreads();
    if (tid < 128) {
        float a = b4[tid];
        for (int k = 0; k < 256; ++k) a += pl[k] * w4t[k * 128 + tid];
        zs[tid] = fmaxf(a, 0.0f);
    }
    __syncthreads();
    if (tid < 64) {
        float v = zs[tid] * w5[tid] + zs[tid + 64] * w5[tid + 64];
#pragma unroll
        for (int off = 32; off > 0; off >>= 1) v += __shfl_down(v, off);
        if (tid == 0) out[g] = 1.0f / (1.0f + expf(-(v + b5[0])));
    }
}

extern "C" void kernel_launch(void* const* d_in, const int* in_sizes, int n_in,
                              void* d_out, int out_size, void* d_ws, size_t ws_size,
                              hipStream_t stream)
{
    const float* x    = (const float*)d_in[0];
    const int*   ei   = (const int*)d_in[1];
    const float* ea   = (const float*)d_in[2];
    const int*   batch= (const int*)d_in[3];
    const float* we1  = (const float*)d_in[4];
    const float* be1  = (const float*)d_in[5];
    const float* wn1  = (const float*)d_in[6];
    const float* bnb1 = (const float*)d_in[7];
    const float* we2  = (const float*)d_in[8];
    const float* be2  = (const float*)d_in[9];
    const float* wn2  = (const float*)d_in[10];
    const float* bnb2 = (const float*)d_in[11];
    const float* we3  = (const float*)d_in[12];
    const float* be3  = (const float*)d_in[13];
    const float* wn3  = (const float*)d_in[14];
    const float* bnb3 = (const float*)d_in[15];
    const float* g1 = (const float*)d_in[16];
    const float* b1 = (const float*)d_in[17];
    const float* rm1= (const float*)d_in[18];
    const float* rv1= (const float*)d_in[19];
    const float* g2 = (const float*)d_in[20];
    const float* b2 = (const float*)d_in[21];
    const float* rm2= (const float*)d_in[22];
    const float* rv2= (const float*)d_in[23];
    const float* g3 = (const float*)d_in[24];
    const float* b3 = (const float*)d_in[25];
    const float* rm3= (const float*)d_in[26];
    const float* rv3= (const float*)d_in[27];
    const float* w4 = (const float*)d_in[28];
    const float* b4 = (const float*)d_in[29];
    const float* w5 = (const float*)d_in[30];
    const float* b5 = (const float*)d_in[31];

    const int N = in_sizes[0] / 64;
    const int E = in_sizes[1] / 2;
    const int G = out_size;

    // workspace layout
    float* ws   = (float*)d_ws;
    float* aggr = ws;                                 // N*256 f32
    float* Wt   = aggr + (size_t)N * 256;             // 256*256 f32
    float* w4t  = Wt + 256 * 256;                     // 256*128 f32
    float* ea_s = w4t + 256 * 128;                    // E*32 f32
    unsigned short* hbuf = (unsigned short*)(ea_s + (size_t)E * 32);  // N*256 bf16
    int* iws    = (int*)(hbuf + (size_t)N * 256);
    int* ideg   = iws;                                // N
    int* rowptr = ideg + N;                           // N+1
    int* cursor = rowptr + N + 1;                     // N
    int* eid_s  = cursor + N;                         // E
    int* esrc_s = eid_s + E;                          // E
    int* gcnt   = esrc_s + E;                         // G
    int* gptr   = gcnt + G;                           // G+1

    const int nblk = (N + 31) / 32;

    // ---- CSR build + graph ranges + edge-feature permute ----
    k_zero_i<<<64, 256, 0, stream>>>(ideg, N);
    k_zero_i<<<4, 256, 0, stream>>>(gcnt, G);
    k_hist<<<512, 256, 0, stream>>>(ei + E, ideg, E);
    k_hist<<<128, 256, 0, stream>>>(batch, gcnt, N);
    k_scan<<<1, 1024, 0, stream>>>(ideg, rowptr, N);
    k_scan<<<1, 1024, 0, stream>>>(gcnt, gptr, G);
    k_copy_i<<<64, 256, 0, stream>>>(rowptr, cursor, N);
    k_scatter<<<512, 256, 0, stream>>>(ei, E, cursor, eid_s, esrc_s);
    k_permute_ea<<<2048, 256, 0, stream>>>(ea, eid_s, ea_s, E);

    // ---- Layer 1 (d_in = 64) ----
    k_gather64<<<1280, 256, 0, stream>>>(x, rowptr, esrc_s, ea_s, we1, be1, aggr, N);
    k_transpose<<<(256 * 64 + 255) / 256, 256, 0, stream>>>(wn1, Wt, 256, 64);
    k_node<64><<<nblk, 256, 0, stream>>>(aggr, Wt, bnb1, g1, b1, rm1, rv1, hbuf, N);

    // ---- Layer 2 ----
    k_gather256<<<2560, 256, 0, stream>>>(hbuf, rowptr, esrc_s, ea_s, we2, be2, aggr, N);
    k_transpose<<<(256 * 256 + 255) / 256, 256, 0, stream>>>(wn2, Wt, 256, 256);
    k_node<256><<<nblk, 256, 0, stream>>>(aggr, Wt, bnb2, g2, b2, rm2, rv2, hbuf, N);

    // ---- Layer 3 ----
    k_gather256<<<2560, 256, 0, stream>>>(hbuf, rowptr, esrc_s, ea_s, we3, be3, aggr, N);
    k_transpose<<<(256 * 256 + 255) / 256, 256, 0, stream>>>(wn3, Wt, 256, 256);
    k_node<256><<<nblk, 256, 0, stream>>>(aggr, Wt, bnb3, g3, b3, rm3, rv3, hbuf, N);

    // ---- Fused pool + head ----
    k_transpose<<<(128 * 256 + 255) / 256, 256, 0, stream>>>(w4, w4t, 128, 256);
    k_pool_head<<<G, 256, 0, stream>>>(hbuf, gptr, w4t, b4, w5, b5, (float*)d_out);
}

// Round 4
// 519.891 us; speedup vs baseline: 1.5960x; 1.5960x over previous
//
#include <hip/hip_runtime.h>
#include <hip/hip_bf16.h>
#include <math.h>

// ---------------------------------------------------------------------------
// GINE model: 3x (GINEConv + BN + ReLU) -> global mean pool -> MLP -> sigmoid
// Round 4: edge-tile MFMA kernel (bf16 16x16x32), LDS-staged h[src], segmented
// sum over sorted dst (atomics only at tile boundaries), self-term folded into
// node-GEMM epilogue.
// ---------------------------------------------------------------------------

typedef __attribute__((ext_vector_type(8))) short short8v;
typedef __attribute__((ext_vector_type(4))) float f32x4;
typedef __attribute__((ext_vector_type(4))) unsigned short us4;

static __device__ __forceinline__ float bf2f(unsigned short u) {
    union { unsigned int u32; float f; } c; c.u32 = ((unsigned int)u) << 16; return c.f;
}
static __device__ __forceinline__ unsigned short f2bf(float f) {
    union { float f; unsigned int u; } c; c.f = f;
    unsigned int lsb = (c.u >> 16) & 1u;
    c.u += 0x7fffu + lsb;
    return (unsigned short)(c.u >> 16);
}

__global__ void k_zero_i(int* __restrict__ p, int n) {
    int i = blockIdx.x * blockDim.x + threadIdx.x;
    int st = gridDim.x * blockDim.x;
    for (; i < n; i += st) p[i] = 0;
}

__global__ void k_copy_i(const int* __restrict__ s, int* __restrict__ d, int n) {
    int i = blockIdx.x * blockDim.x + threadIdx.x;
    int st = gridDim.x * blockDim.x;
    for (; i < n; i += st) d[i] = s[i];
}

__global__ void k_copy_f4(const float* __restrict__ s, float* __restrict__ d, int n4) {
    int i = blockIdx.x * blockDim.x + threadIdx.x;
    int st = gridDim.x * blockDim.x;
    const float4* s4 = (const float4*)s;
    float4* d4 = (float4*)d;
    for (; i < n4; i += st) d4[i] = s4[i];
}

// f32 -> bf16 cast, 4 elems per thread
__global__ void k_cast_bf(const float* __restrict__ s, unsigned short* __restrict__ d, int n4) {
    int i = blockIdx.x * blockDim.x + threadIdx.x;
    int st = gridDim.x * blockDim.x;
    for (; i < n4; i += st) {
        float4 t = ((const float4*)s)[i];
        us4 o; o.x = f2bf(t.x); o.y = f2bf(t.y); o.z = f2bf(t.z); o.w = f2bf(t.w);
        ((us4*)d)[i] = o;
    }
}

// transpose W[J][K] -> Wt[K][J]
__global__ void k_transpose(const float* __restrict__ W, float* __restrict__ Wt, int J, int K) {
    int idx = blockIdx.x * blockDim.x + threadIdx.x;
    if (idx < J * K) {
        int j = idx / K, k = idx % K;
        Wt[k * J + j] = W[idx];
    }
}

__global__ void k_hist(const int* __restrict__ v, int* __restrict__ cnt, int n) {
    int i = blockIdx.x * blockDim.x + threadIdx.x;
    int st = gridDim.x * blockDim.x;
    for (; i < n; i += st) atomicAdd(&cnt[v[i]], 1);
}

// single-block exclusive scan, out has n+1 entries (out[n] = total)
__global__ __launch_bounds__(1024) void k_scan(const int* __restrict__ in,
                                               int* __restrict__ out, int n) {
    __shared__ int wsum[16];
    __shared__ int carry_s;
    const int tid = threadIdx.x;
    const int lane = tid & 63, wv = tid >> 6;
    if (tid == 0) carry_s = 0;
    __syncthreads();
    for (int base = 0; base < n; base += 1024) {
        int idx = base + tid;
        int v = (idx < n) ? in[idx] : 0;
        int s = v;
#pragma unroll
        for (int off = 1; off < 64; off <<= 1) {
            int t = __shfl_up(s, off);
            if (lane >= off) s += t;
        }
        if (lane == 63) wsum[wv] = s;
        __syncthreads();
        int woff = 0;
        for (int i = 0; i < wv; ++i) woff += wsum[i];
        int carry = carry_s;
        if (idx < n) out[idx] = carry + woff + s - v;
        __syncthreads();
        if (tid == 1023) carry_s = carry + woff + s;
        __syncthreads();
    }
    if (tid == 0) out[n] = carry_s;
}

// bucket edges by dst; record permuted src and dst
__global__ void k_scatter(const int* __restrict__ ei, int E, int* __restrict__ cursor,
                          int* __restrict__ eid_s, int* __restrict__ esrc_s,
                          int* __restrict__ dst_s) {
    int i = blockIdx.x * blockDim.x + threadIdx.x;
    int st = gridDim.x * blockDim.x;
    for (; i < E; i += st) {
        int d = ei[E + i];
        int pos = atomicAdd(&cursor[d], 1);
        eid_s[pos] = i;
        esrc_s[pos] = ei[i];
        dst_s[pos] = d;
    }
}

// ea_s[pos] = bf16(ea[eid_s[pos]]), CSR order; 8-elem granules
__global__ void k_permute_ea(const float* __restrict__ ea, const int* __restrict__ eid_s,
                             unsigned short* __restrict__ ea_s, int E) {
    int i = blockIdx.x * blockDim.x + threadIdx.x;
    int st = gridDim.x * blockDim.x;
    const int ng = E * 4;   // 8 elems per granule
    for (; i < ng; i += st) {
        int pos = i >> 2, q = i & 3;
        int e = eid_s[pos];
        const float4* sp = (const float4*)(ea + (size_t)e * 32 + q * 8);
        float4 a = sp[0], b = sp[1];
        us4 o0, o1;
        o0.x = f2bf(a.x); o0.y = f2bf(a.y); o0.z = f2bf(a.z); o0.w = f2bf(a.w);
        o1.x = f2bf(b.x); o1.y = f2bf(b.y); o1.z = f2bf(b.z); o1.w = f2bf(b.w);
        us4* dp = (us4*)(ea_s + (size_t)pos * 32 + q * 8);
        dp[0] = o0; dp[1] = o1;
    }
}

// ---------------------------------------------------------------------------
// Edge-tile MFMA kernel. D=256: EB=64 edges/block; D=64: EB=256.
// aggr must be pre-initialized with the self term h (f32).
// m[e][c] = relu( h[src[e]][c] + (ea[e] @ we.T)[c] + be[c] ), segment-summed
// by sorted dst into aggr. Interior segments: plain +=; boundary: atomicAdd.
// ---------------------------------------------------------------------------
template<int D>
__global__ __launch_bounds__(256) void k_edge_mfma(
    const unsigned short* __restrict__ hbf,   // [N][D] bf16
    const unsigned short* __restrict__ ea_s,  // [E][32] bf16, CSR order
    const int* __restrict__ esrc_s,           // [E]
    const int* __restrict__ dst_s,            // [E]
    const unsigned short* __restrict__ webf,  // [D][32] bf16 (row c = we[c][:])
    const float* __restrict__ be,             // [D]
    float* __restrict__ aggr,                 // [N][D] f32
    int E)
{
    constexpr int EB = (D == 256) ? 64 : 256;
    constexpr int RPW = EB / 4;               // h rows staged per wave
    __shared__ unsigned short m_lds[EB][D];
    __shared__ int src_lds[EB];
    __shared__ int dst_lds[EB];

    const int tid = threadIdx.x;
    const int lane = tid & 63;
    const int w = tid >> 6;
    const int e0 = blockIdx.x * EB;
    const int nE = min(EB, E - e0);
    const int l15 = lane & 15;
    const int lhi = lane >> 4;

    for (int i = tid; i < EB; i += 256) {
        int ge = e0 + i;
        src_lds[i] = (ge < E) ? esrc_s[ge] : 0;
        dst_lds[i] = (ge < E) ? dst_s[ge] : -1;
    }

    // B fragments (weights) + bias per col-tile
    short8v bfr[4]; float bias[4]; int colb[4];
#pragma unroll
    for (int t = 0; t < 4; ++t) {
        int ctg = (D == 256) ? (w * 4 + t) : t;
        int c = ctg * 16 + l15;
        bfr[t] = *(const short8v*)(webf + c * 32 + lhi * 8);
        bias[t] = be[c];
        colb[t] = ctg * 16;
    }
    // A fragments (edge features)
    short8v afr[4];
#pragma unroll
    for (int q = 0; q < 4; ++q) {
        int etg = (D == 256) ? q : (w * 4 + q);
        int er = etg * 16 + l15;
        int ge = e0 + er;
        if (ge >= E) ge = E - 1;
        afr[q] = *(const short8v*)(ea_s + (size_t)ge * 32 + lhi * 8);
    }

    __syncthreads();   // src_lds/dst_lds visible

    // stage h[src] rows into LDS (coalesced per row)
    for (int r = w * RPW; r < w * RPW + RPW; ++r) {
        if (r < nE) {
            int s = src_lds[r];
            if (D == 256)
                *(us4*)&m_lds[r][lane * 4] = *(const us4*)(hbf + (size_t)s * 256 + lane * 4);
            else
                m_lds[r][lane] = hbf[(size_t)s * 64 + lane];
        }
    }

    // MFMA while h loads are in flight; bias folded into C-init
    f32x4 acc[4][4];
#pragma unroll
    for (int q = 0; q < 4; ++q) {
#pragma unroll
        for (int t = 0; t < 4; ++t) {
            f32x4 ci;
            ci[0] = bias[t]; ci[1] = bias[t]; ci[2] = bias[t]; ci[3] = bias[t];
            acc[q][t] = __builtin_amdgcn_mfma_f32_16x16x32_bf16(afr[q], bfr[t], ci, 0, 0, 0);
        }
    }

    __syncthreads();   // all h rows staged

    // m = relu(el + h_src), written in place (1:1 lane->element, no race)
#pragma unroll
    for (int q = 0; q < 4; ++q) {
        int etg = (D == 256) ? q : (w * 4 + q);
#pragma unroll
        for (int t = 0; t < 4; ++t) {
#pragma unroll
            for (int i = 0; i < 4; ++i) {
                int er = etg * 16 + lhi * 4 + i;
                int c = colb[t] + l15;
                if (er < nE) {
                    float mv = acc[q][t][i] + bf2f(m_lds[er][c]);
                    m_lds[er][c] = f2bf(fmaxf(mv, 0.0f));
                }
            }
        }
    }

    __syncthreads();

    // segmented sum over sorted dst, 64-edge subranges
    const int c = (D == 256) ? tid : (tid & 63);
    const int sub = (D == 256) ? 0 : (tid >> 6);
    const int sb = sub * 64;
    const int se = min(sb + 64, nE);
    float a2 = 0.0f;
    int segstart = sb;
    for (int e = sb; e < se; ++e) {
        a2 += bf2f(m_lds[e][c]);
        bool fin = (e == se - 1) || (dst_lds[e + 1] != dst_lds[e]);
        if (fin) {
            float* p = aggr + (size_t)dst_lds[e] * D + c;
            if (segstart == sb || e == se - 1) atomicAdd(p, a2);
            else *p += a2;     // segment fully interior -> exclusively owned
            a2 = 0.0f;
            segstart = e + 1;
        }
    }
}

// Node GEMM + BN + ReLU -> h bf16 (+ optional f32 aggr-init for next layer).
template<int K, bool AW>
__global__ __launch_bounds__(256) void k_node(
    const float* __restrict__ A, const float* __restrict__ Wt,
    const float* __restrict__ bnb, const float* __restrict__ g,
    const float* __restrict__ b, const float* __restrict__ rm,
    const float* __restrict__ rv, unsigned short* __restrict__ out,
    float* __restrict__ aggr_out, int N)
{
    __shared__ float As[32 * K];
    const int tid = threadIdx.x;
    const int lane = tid & 63;
    const int grp = tid >> 6;
    const int row0 = blockIdx.x * 32;
    const int nrows = min(32, N - row0);
    const int r0 = grp * 8;

    if (nrows == 32) {
        const float4* Ag = (const float4*)(A + (size_t)row0 * K);
        float4* As4 = (float4*)As;
        for (int i = tid; i < 32 * K / 4; i += 256) As4[i] = Ag[i];
    } else {
        for (int i = tid; i < nrows * K; i += 256) As[i] = A[(size_t)row0 * K + i];
    }
    __syncthreads();

    float acc[8][4];
#pragma unroll
    for (int i = 0; i < 8; ++i)
#pragma unroll
        for (int j = 0; j < 4; ++j) acc[i][j] = 0.0f;

    for (int k = 0; k < K; k += 4) {
        float wreg[4][4];
#pragma unroll
        for (int kk = 0; kk < 4; ++kk)
#pragma unroll
            for (int j = 0; j < 4; ++j)
                wreg[kk][j] = Wt[(k + kk) * 256 + lane + 64 * j];
#pragma unroll
        for (int i = 0; i < 8; ++i) {
            float4 a = *(const float4*)&As[(r0 + i) * K + k];
#pragma unroll
            for (int j = 0; j < 4; ++j)
                acc[i][j] += a.x * wreg[0][j] + a.y * wreg[1][j]
                           + a.z * wreg[2][j] + a.w * wreg[3][j];
        }
    }

    float bias[4], scale[4], shift[4];
#pragma unroll
    for (int j = 0; j < 4; ++j) {
        int cc = lane + 64 * j;
        bias[j] = bnb[cc];
        scale[j] = g[cc] * rsqrtf(rv[cc] + 1e-5f);
        shift[j] = b[cc] - rm[cc] * scale[j];
    }
#pragma unroll
    for (int i = 0; i < 8; ++i) {
        int row = row0 + r0 + i;
        if (row < N) {
#pragma unroll
            for (int j = 0; j < 4; ++j) {
                float v = (acc[i][j] + bias[j]) * scale[j] + shift[j];
                v = fmaxf(v, 0.0f);
                out[(size_t)row * 256 + lane + 64 * j] = f2bf(v);
                if (AW) aggr_out[(size_t)row * 256 + lane + 64 * j] = v;
            }
        }
    }
}

// Fused global-mean-pool + MLP head (h in bf16).
__global__ __launch_bounds__(256) void k_pool_head(
    const unsigned short* __restrict__ h, const int* __restrict__ gptr,
    const float* __restrict__ w4t, const float* __restrict__ b4,
    const float* __restrict__ w5, const float* __restrict__ b5,
    float* __restrict__ out)
{
    __shared__ float pl[256];
    __shared__ float zs[128];
    const int g = blockIdx.x;
    const int tid = threadIdx.x;
    int beg = gptr[g], end = gptr[g + 1];
    float acc = 0.0f;
    for (int r = beg; r < end; ++r) acc += bf2f(h[(size_t)r * 256 + tid]);
    float cnt = (float)(end - beg);
    pl[tid] = acc / fmaxf(cnt, 1.0f);
    __syncthreads();
    if (tid < 128) {
        float a = b4[tid];
        for (int k = 0; k < 256; ++k) a += pl[k] * w4t[k * 128 + tid];
        zs[tid] = fmaxf(a, 0.0f);
    }
    __syncthreads();
    if (tid < 64) {
        float v = zs[tid] * w5[tid] + zs[tid + 64] * w5[tid + 64];
#pragma unroll
        for (int off = 32; off > 0; off >>= 1) v += __shfl_down(v, off);
        if (tid == 0) out[g] = 1.0f / (1.0f + expf(-(v + b5[0])));
    }
}

extern "C" void kernel_launch(void* const* d_in, const int* in_sizes, int n_in,
                              void* d_out, int out_size, void* d_ws, size_t ws_size,
                              hipStream_t stream)
{
    const float* x    = (const float*)d_in[0];
    const int*   ei   = (const int*)d_in[1];
    const float* ea   = (const float*)d_in[2];
    const int*   batch= (const int*)d_in[3];
    const float* we1  = (const float*)d_in[4];
    const float* be1  = (const float*)d_in[5];
    const float* wn1  = (const float*)d_in[6];
    const float* bnb1 = (const float*)d_in[7];
    const float* we2  = (const float*)d_in[8];
    const float* be2  = (const float*)d_in[9];
    const float* wn2  = (const float*)d_in[10];
    const float* bnb2 = (const float*)d_in[11];
    const float* we3  = (const float*)d_in[12];
    const float* be3  = (const float*)d_in[13];
    const float* wn3  = (const float*)d_in[14];
    const float* bnb3 = (const float*)d_in[15];
    const float* g1 = (const float*)d_in[16];
    const float* b1 = (const float*)d_in[17];
    const float* rm1= (const float*)d_in[18];
    const float* rv1= (const float*)d_in[19];
    const float* g2 = (const float*)d_in[20];
    const float* b2 = (const float*)d_in[21];
    const float* rm2= (const float*)d_in[22];
    const float* rv2= (const float*)d_in[23];
    const float* g3 = (const float*)d_in[24];
    const float* b3 = (const float*)d_in[25];
    const float* rm3= (const float*)d_in[26];
    const float* rv3= (const float*)d_in[27];
    const float* w4 = (const float*)d_in[28];
    const float* b4 = (const float*)d_in[29];
    const float* w5 = (const float*)d_in[30];
    const float* b5 = (const float*)d_in[31];

    const int N = in_sizes[0] / 64;
    const int E = in_sizes[1] / 2;
    const int G = out_size;

    // ---- workspace layout ----
    float* ws    = (float*)d_ws;
    float* aggrA = ws;                                  // N*256 f32 (first N*64 = layer-1 aggr)
    float* aggrB = aggrA + (size_t)N * 256;             // N*256 f32
    float* Wt    = aggrB + (size_t)N * 256;             // 256*256
    float* w4t   = Wt + 256 * 256;                      // 256*128
    unsigned short* ea_s  = (unsigned short*)(w4t + 256 * 128);   // E*32 bf16
    unsigned short* x_bf  = ea_s + (size_t)E * 32;      // N*64 bf16
    unsigned short* h_bf  = x_bf + (size_t)N * 64;      // N*256 bf16
    unsigned short* webf1 = h_bf + (size_t)N * 256;     // 64*32 bf16
    unsigned short* webf2 = webf1 + 64 * 32;            // 256*32
    unsigned short* webf3 = webf2 + 256 * 32;           // 256*32
    int* iws    = (int*)(webf3 + 256 * 32);
    int* ideg   = iws;                                  // N
    int* rowptr = ideg + N;                             // N+1
    int* cursor = rowptr + N + 1;                       // N
    int* eid_s  = cursor + N;                           // E
    int* esrc_s = eid_s + E;                            // E
    int* dst_s  = esrc_s + E;                           // E
    int* gcnt   = dst_s + E;                            // G
    int* gptr   = gcnt + G;                             // G+1

    const int nblk = (N + 31) / 32;

    // ---- CSR build + graph ranges + casts ----
    k_zero_i<<<64, 256, 0, stream>>>(ideg, N);
    k_zero_i<<<4, 256, 0, stream>>>(gcnt, G);
    k_hist<<<512, 256, 0, stream>>>(ei + E, ideg, E);
    k_hist<<<128, 256, 0, stream>>>(batch, gcnt, N);
    k_scan<<<1, 1024, 0, stream>>>(ideg, rowptr, N);
    k_scan<<<1, 1024, 0, stream>>>(gcnt, gptr, G);
    k_copy_i<<<64, 256, 0, stream>>>(rowptr, cursor, N);
    k_scatter<<<512, 256, 0, stream>>>(ei, E, cursor, eid_s, esrc_s, dst_s);
    k_permute_ea<<<2048, 256, 0, stream>>>(ea, eid_s, ea_s, E);
    k_cast_bf<<<512, 256, 0, stream>>>(x, x_bf, N * 64 / 4);
    k_cast_bf<<<2, 256, 0, stream>>>(we1, webf1, 64 * 32 / 4);
    k_cast_bf<<<8, 256, 0, stream>>>(we2, webf2, 256 * 32 / 4);
    k_cast_bf<<<8, 256, 0, stream>>>(we3, webf3, 256 * 32 / 4);
    k_copy_f4<<<512, 256, 0, stream>>>(x, aggrA, N * 64 / 4);   // layer-1 self term

    // ---- Layer 1 (D=64) ----
    k_edge_mfma<64><<<(E + 255) / 256, 256, 0, stream>>>(
        x_bf, ea_s, esrc_s, dst_s, webf1, be1, aggrA, E);
    k_transpose<<<(256 * 64 + 255) / 256, 256, 0, stream>>>(wn1, Wt, 256, 64);
    k_node<64, true><<<nblk, 256, 0, stream>>>(aggrA, Wt, bnb1, g1, b1, rm1, rv1,
                                               h_bf, aggrB, N);

    // ---- Layer 2 (D=256) ----
    k_edge_mfma<256><<<(E + 63) / 64, 256, 0, stream>>>(
        h_bf, ea_s, esrc_s, dst_s, webf2, be2, aggrB, E);
    k_transpose<<<(256 * 256 + 255) / 256, 256, 0, stream>>>(wn2, Wt, 256, 256);
    k_node<256, true><<<nblk, 256, 0, stream>>>(aggrB, Wt, bnb2, g2, b2, rm2, rv2,
                                                h_bf, aggrA, N);

    // ---- Layer 3 (D=256) ----
    k_edge_mfma<256><<<(E + 63) / 64, 256, 0, stream>>>(
        h_bf, ea_s, esrc_s, dst_s, webf3, be3, aggrA, E);
    k_transpose<<<(256 * 256 + 255) / 256, 256, 0, stream>>>(wn3, Wt, 256, 256);
    k_node<256, false><<<nblk, 256, 0, stream>>>(aggrA, Wt, bnb3, g3, b3, rm3, rv3,
                                                 h_bf, (float*)nullptr, N);

    // ---- Fused pool + head ----
    k_transpose<<<(128 * 256 + 255) / 256, 256, 0, stream>>>(w4, w4t, 128, 256);
    k_pool_head<<<G, 256, 0, stream>>>(h_bf, gptr, w4t, b4, w5, b5, (float*)d_out);
}

// Round 5
// 405.000 us; speedup vs baseline: 2.0488x; 1.2837x over previous
//
#include <hip/hip_runtime.h>
#include <hip/hip_bf16.h>
#include <math.h>

// ---------------------------------------------------------------------------
// GINE model: 3x (GINEConv + BN + ReLU) -> global mean pool -> MLP -> sigmoid
// Round 5: barrier-free, LDS-free edge kernel. Per 64-edge tile each wave owns
// a 64-col slice: MFMA edge-linear, register h-gather, in-register segmented
// sum over sorted dst (ballot/popcount segment ids), atomicAdd flush.
// ---------------------------------------------------------------------------

typedef __attribute__((ext_vector_type(8))) short short8v;
typedef __attribute__((ext_vector_type(4))) float f32x4;
typedef __attribute__((ext_vector_type(4))) unsigned short us4;

static __device__ __forceinline__ float bf2f(unsigned short u) {
    union { unsigned int u32; float f; } c; c.u32 = ((unsigned int)u) << 16; return c.f;
}
static __device__ __forceinline__ unsigned short f2bf(float f) {
    union { float f; unsigned int u; } c; c.f = f;
    unsigned int lsb = (c.u >> 16) & 1u;
    c.u += 0x7fffu + lsb;
    return (unsigned short)(c.u >> 16);
}

__global__ void k_zero_i(int* __restrict__ p, int n) {
    int i = blockIdx.x * blockDim.x + threadIdx.x;
    int st = gridDim.x * blockDim.x;
    for (; i < n; i += st) p[i] = 0;
}

__global__ void k_copy_i(const int* __restrict__ s, int* __restrict__ d, int n) {
    int i = blockIdx.x * blockDim.x + threadIdx.x;
    int st = gridDim.x * blockDim.x;
    for (; i < n; i += st) d[i] = s[i];
}

__global__ void k_copy_f4(const float* __restrict__ s, float* __restrict__ d, int n4) {
    int i = blockIdx.x * blockDim.x + threadIdx.x;
    int st = gridDim.x * blockDim.x;
    const float4* s4 = (const float4*)s;
    float4* d4 = (float4*)d;
    for (; i < n4; i += st) d4[i] = s4[i];
}

__global__ void k_cast_bf(const float* __restrict__ s, unsigned short* __restrict__ d, int n4) {
    int i = blockIdx.x * blockDim.x + threadIdx.x;
    int st = gridDim.x * blockDim.x;
    for (; i < n4; i += st) {
        float4 t = ((const float4*)s)[i];
        us4 o; o.x = f2bf(t.x); o.y = f2bf(t.y); o.z = f2bf(t.z); o.w = f2bf(t.w);
        ((us4*)d)[i] = o;
    }
}

// transpose W[J][K] -> Wt[K][J]
__global__ void k_transpose(const float* __restrict__ W, float* __restrict__ Wt, int J, int K) {
    int idx = blockIdx.x * blockDim.x + threadIdx.x;
    if (idx < J * K) {
        int j = idx / K, k = idx % K;
        Wt[k * J + j] = W[idx];
    }
}

__global__ void k_hist(const int* __restrict__ v, int* __restrict__ cnt, int n) {
    int i = blockIdx.x * blockDim.x + threadIdx.x;
    int st = gridDim.x * blockDim.x;
    for (; i < n; i += st) atomicAdd(&cnt[v[i]], 1);
}

// single-block exclusive scan, out has n+1 entries (out[n] = total)
__global__ __launch_bounds__(1024) void k_scan(const int* __restrict__ in,
                                               int* __restrict__ out, int n) {
    __shared__ int wsum[16];
    __shared__ int carry_s;
    const int tid = threadIdx.x;
    const int lane = tid & 63, wv = tid >> 6;
    if (tid == 0) carry_s = 0;
    __syncthreads();
    for (int base = 0; base < n; base += 1024) {
        int idx = base + tid;
        int v = (idx < n) ? in[idx] : 0;
        int s = v;
#pragma unroll
        for (int off = 1; off < 64; off <<= 1) {
            int t = __shfl_up(s, off);
            if (lane >= off) s += t;
        }
        if (lane == 63) wsum[wv] = s;
        __syncthreads();
        int woff = 0;
        for (int i = 0; i < wv; ++i) woff += wsum[i];
        int carry = carry_s;
        if (idx < n) out[idx] = carry + woff + s - v;
        __syncthreads();
        if (tid == 1023) carry_s = carry + woff + s;
        __syncthreads();
    }
    if (tid == 0) out[n] = carry_s;
}

// bucket edges by dst; record permuted src and dst
__global__ void k_scatter(const int* __restrict__ ei, int E, int* __restrict__ cursor,
                          int* __restrict__ eid_s, int* __restrict__ esrc_s,
                          int* __restrict__ dst_s) {
    int i = blockIdx.x * blockDim.x + threadIdx.x;
    int st = gridDim.x * blockDim.x;
    for (; i < E; i += st) {
        int d = ei[E + i];
        int pos = atomicAdd(&cursor[d], 1);
        eid_s[pos] = i;
        esrc_s[pos] = ei[i];
        dst_s[pos] = d;
    }
}

// pad tail rows [E, Epad): src=0, dst=-1, ea_s row = 0
__global__ void k_pad_tail(int* __restrict__ esrc_s, int* __restrict__ dst_s,
                           unsigned short* __restrict__ ea_s, int E, int Epad) {
    int i = E + threadIdx.x;
    if (i < Epad) {
        esrc_s[i] = 0;
        dst_s[i] = -1;
        for (int q = 0; q < 32; ++q) ea_s[(size_t)i * 32 + q] = 0;
    }
}

// ea_s[pos] = bf16(ea[eid_s[pos]]), CSR order; 8-elem granules
__global__ void k_permute_ea(const float* __restrict__ ea, const int* __restrict__ eid_s,
                             unsigned short* __restrict__ ea_s, int E) {
    int i = blockIdx.x * blockDim.x + threadIdx.x;
    int st = gridDim.x * blockDim.x;
    const int ng = E * 4;
    for (; i < ng; i += st) {
        int pos = i >> 2, q = i & 3;
        int e = eid_s[pos];
        const float4* sp = (const float4*)(ea + (size_t)e * 32 + q * 8);
        float4 a = sp[0], b = sp[1];
        us4 o0, o1;
        o0.x = f2bf(a.x); o0.y = f2bf(a.y); o0.z = f2bf(a.z); o0.w = f2bf(a.w);
        o1.x = f2bf(b.x); o1.y = f2bf(b.y); o1.z = f2bf(b.z); o1.w = f2bf(b.w);
        us4* dp = (us4*)(ea_s + (size_t)pos * 32 + q * 8);
        dp[0] = o0; dp[1] = o1;
    }
}

// ---------------------------------------------------------------------------
// Barrier-free edge kernel. Tile = 64 edges. D=256: block's 4 waves split the
// 256 cols (64 each). D=64: each wave owns a whole tile.
// aggr must be pre-initialized with the self term (f32).
// ---------------------------------------------------------------------------
template<int D>
__global__ __launch_bounds__(256) void k_edge_mfma(
    const unsigned short* __restrict__ hbf,   // [N][D] bf16
    const unsigned short* __restrict__ ea_s,  // [Epad][32] bf16, CSR order
    const int* __restrict__ esrc_s,           // [Epad]
    const int* __restrict__ dst_s,            // [Epad]
    const unsigned short* __restrict__ webf,  // [D][32] bf16
    const float* __restrict__ be,             // [D]
    float* __restrict__ aggr,                 // [N][D] f32
    int E)
{
    const int tid = threadIdx.x;
    const int lane = tid & 63;
    const int w = tid >> 6;
    const int l15 = lane & 15;
    const int lhi = lane >> 4;

    const int wavetile = (D == 256) ? (int)blockIdx.x : ((int)blockIdx.x * 4 + w);
    const int colbase  = (D == 256) ? (w * 64) : 0;
    const int e0 = wavetile * 64;
    if (e0 >= E) return;

    // per-lane dst (row = lane of this tile)
    const int dstreg = dst_s[e0 + lane];

    // src rows, 4 consecutive per q-tile via int4
    int4 src4[4];
#pragma unroll
    for (int q = 0; q < 4; ++q)
        src4[q] = *(const int4*)(esrc_s + e0 + q * 16 + lhi * 4);

    // A fragments (edge features, padded rows are zero)
    short8v afr[4];
#pragma unroll
    for (int q = 0; q < 4; ++q)
        afr[q] = *(const short8v*)(ea_s + (size_t)(e0 + q * 16 + l15) * 32 + lhi * 8);

    // B fragments (weights) + bias
    short8v bfr[4]; float bias[4];
#pragma unroll
    for (int t = 0; t < 4; ++t) {
        int c = colbase + t * 16 + l15;
        bfr[t] = *(const short8v*)(webf + (size_t)c * 32 + lhi * 8);
        bias[t] = be[c];
    }

    // register h-gather in fragment layout: hv[q][i][t]
    unsigned short hv[4][4][4];
#pragma unroll
    for (int q = 0; q < 4; ++q) {
        const int sr[4] = {src4[q].x, src4[q].y, src4[q].z, src4[q].w};
#pragma unroll
        for (int i = 0; i < 4; ++i) {
            const unsigned short* hp = hbf + (size_t)sr[i] * D + colbase + l15;
#pragma unroll
            for (int t = 0; t < 4; ++t) hv[q][i][t] = hp[t * 16];
        }
    }

    // MFMA, bias folded into C-init
    f32x4 acc[4][4];
#pragma unroll
    for (int q = 0; q < 4; ++q)
#pragma unroll
        for (int t = 0; t < 4; ++t) {
            f32x4 ci; ci[0] = bias[t]; ci[1] = bias[t]; ci[2] = bias[t]; ci[3] = bias[t];
            acc[q][t] = __builtin_amdgcn_mfma_f32_16x16x32_bf16(afr[q], bfr[t], ci, 0, 0, 0);
        }

    // m = relu(el + h_src), in-register
#pragma unroll
    for (int q = 0; q < 4; ++q)
#pragma unroll
        for (int t = 0; t < 4; ++t)
#pragma unroll
            for (int i = 0; i < 4; ++i)
                acc[q][t][i] = fmaxf(acc[q][t][i] + bf2f(hv[q][i][t]), 0.0f);

    // segment structure over sorted dst (uniform across lanes)
    int dprev = __shfl_up(dstreg, 1);
    bool bflag = (lane > 0) && (dstreg != dprev);
    unsigned long long bmask = __ballot(bflag);
    const int nseg = __builtin_popcountll(bmask) + 1;
    unsigned mlo = (unsigned)bmask, mhi = (unsigned)(bmask >> 32);
    const int segid_lane =
        __builtin_amdgcn_mbcnt_hi(mhi, __builtin_amdgcn_mbcnt_lo(mlo, 0)) + (bflag ? 1 : 0);

    int segid_qi[4][4];
#pragma unroll
    for (int q = 0; q < 4; ++q)
#pragma unroll
        for (int i = 0; i < 4; ++i) {
            int row = q * 16 + lhi * 4 + i;
            unsigned long long p = 1ull << row;
            segid_qi[q][i] = __builtin_popcountll(bmask & (p | (p - 1ull)));
        }

    for (int s = 0; s < nseg; ++s) {
        float a[4] = {0.0f, 0.0f, 0.0f, 0.0f};
#pragma unroll
        for (int q = 0; q < 4; ++q)
#pragma unroll
            for (int i = 0; i < 4; ++i) {
                bool tk = (segid_qi[q][i] == s);
#pragma unroll
                for (int t = 0; t < 4; ++t) a[t] += tk ? acc[q][t][i] : 0.0f;
            }
#pragma unroll
        for (int t = 0; t < 4; ++t) {
            a[t] += __shfl_xor(a[t], 16);
            a[t] += __shfl_xor(a[t], 32);
        }
        unsigned long long ms = __ballot(segid_lane == s);
        int fl = (int)__builtin_ctzll(ms);
        int dseg = __shfl(dstreg, fl);
        if (dseg >= 0 && lhi == 0) {
#pragma unroll
            for (int t = 0; t < 4; ++t)
                atomicAdd(aggr + (size_t)dseg * D + colbase + t * 16 + l15, a[t]);
        }
    }
}

// Node GEMM + BN + ReLU -> h bf16 (+ optional f32 aggr-init for next layer).
template<int K, bool AW>
__global__ __launch_bounds__(256) void k_node(
    const float* __restrict__ A, const float* __restrict__ Wt,
    const float* __restrict__ bnb, const float* __restrict__ g,
    const float* __restrict__ b, const float* __restrict__ rm,
    const float* __restrict__ rv, unsigned short* __restrict__ out,
    float* __restrict__ aggr_out, int N)
{
    __shared__ float As[32 * K];
    const int tid = threadIdx.x;
    const int lane = tid & 63;
    const int grp = tid >> 6;
    const int row0 = blockIdx.x * 32;
    const int nrows = min(32, N - row0);
    const int r0 = grp * 8;

    if (nrows == 32) {
        const float4* Ag = (const float4*)(A + (size_t)row0 * K);
        float4* As4 = (float4*)As;
        for (int i = tid; i < 32 * K / 4; i += 256) As4[i] = Ag[i];
    } else {
        for (int i = tid; i < nrows * K; i += 256) As[i] = A[(size_t)row0 * K + i];
    }
    __syncthreads();

    float acc[8][4];
#pragma unroll
    for (int i = 0; i < 8; ++i)
#pragma unroll
        for (int j = 0; j < 4; ++j) acc[i][j] = 0.0f;

    for (int k = 0; k < K; k += 4) {
        float wreg[4][4];
#pragma unroll
        for (int kk = 0; kk < 4; ++kk)
#pragma unroll
            for (int j = 0; j < 4; ++j)
                wreg[kk][j] = Wt[(k + kk) * 256 + lane + 64 * j];
#pragma unroll
        for (int i = 0; i < 8; ++i) {
            float4 a = *(const float4*)&As[(r0 + i) * K + k];
#pragma unroll
            for (int j = 0; j < 4; ++j)
                acc[i][j] += a.x * wreg[0][j] + a.y * wreg[1][j]
                           + a.z * wreg[2][j] + a.w * wreg[3][j];
        }
    }

    float bias[4], scale[4], shift[4];
#pragma unroll
    for (int j = 0; j < 4; ++j) {
        int cc = lane + 64 * j;
        bias[j] = bnb[cc];
        scale[j] = g[cc] * rsqrtf(rv[cc] + 1e-5f);
        shift[j] = b[cc] - rm[cc] * scale[j];
    }
#pragma unroll
    for (int i = 0; i < 8; ++i) {
        int row = row0 + r0 + i;
        if (row < N) {
#pragma unroll
            for (int j = 0; j < 4; ++j) {
                float v = (acc[i][j] + bias[j]) * scale[j] + shift[j];
                v = fmaxf(v, 0.0f);
                out[(size_t)row * 256 + lane + 64 * j] = f2bf(v);
                if (AW) aggr_out[(size_t)row * 256 + lane + 64 * j] = v;
            }
        }
    }
}

// Fused global-mean-pool + MLP head (h in bf16).
__global__ __launch_bounds__(256) void k_pool_head(
    const unsigned short* __restrict__ h, const int* __restrict__ gptr,
    const float* __restrict__ w4t, const float* __restrict__ b4,
    const float* __restrict__ w5, const float* __restrict__ b5,
    float* __restrict__ out)
{
    __shared__ float pl[256];
    __shared__ float zs[128];
    const int g = blockIdx.x;
    const int tid = threadIdx.x;
    int beg = gptr[g], end = gptr[g + 1];
    float acc = 0.0f;
    for (int r = beg; r < end; ++r) acc += bf2f(h[(size_t)r * 256 + tid]);
    float cnt = (float)(end - beg);
    pl[tid] = acc / fmaxf(cnt, 1.0f);
    __syncthreads();
    if (tid < 128) {
        float a = b4[tid];
        for (int k = 0; k < 256; ++k) a += pl[k] * w4t[k * 128 + tid];
        zs[tid] = fmaxf(a, 0.0f);
    }
    __syncthreads();
    if (tid < 64) {
        float v = zs[tid] * w5[tid] + zs[tid + 64] * w5[tid + 64];
#pragma unroll
        for (int off = 32; off > 0; off >>= 1) v += __shfl_down(v, off);
        if (tid == 0) out[g] = 1.0f / (1.0f + expf(-(v + b5[0])));
    }
}

extern "C" void kernel_launch(void* const* d_in, const int* in_sizes, int n_in,
                              void* d_out, int out_size, void* d_ws, size_t ws_size,
                              hipStream_t stream)
{
    const float* x    = (const float*)d_in[0];
    const int*   ei   = (const int*)d_in[1];
    const float* ea   = (const float*)d_in[2];
    const int*   batch= (const int*)d_in[3];
    const float* we1  = (const float*)d_in[4];
    const float* be1  = (const float*)d_in[5];
    const float* wn1  = (const float*)d_in[6];
    const float* bnb1 = (const float*)d_in[7];
    const float* we2  = (const float*)d_in[8];
    const float* be2  = (const float*)d_in[9];
    const float* wn2  = (const float*)d_in[10];
    const float* bnb2 = (const float*)d_in[11];
    const float* we3  = (const float*)d_in[12];
    const float* be3  = (const float*)d_in[13];
    const float* wn3  = (const float*)d_in[14];
    const float* bnb3 = (const float*)d_in[15];
    const float* g1 = (const float*)d_in[16];
    const float* b1 = (const float*)d_in[17];
    const float* rm1= (const float*)d_in[18];
    const float* rv1= (const float*)d_in[19];
    const float* g2 = (const float*)d_in[20];
    const float* b2 = (const float*)d_in[21];
    const float* rm2= (const float*)d_in[22];
    const float* rv2= (const float*)d_in[23];
    const float* g3 = (const float*)d_in[24];
    const float* b3 = (const float*)d_in[25];
    const float* rm3= (const float*)d_in[26];
    const float* rv3= (const float*)d_in[27];
    const float* w4 = (const float*)d_in[28];
    const float* b4 = (const float*)d_in[29];
    const float* w5 = (const float*)d_in[30];
    const float* b5 = (const float*)d_in[31];

    const int N = in_sizes[0] / 64;
    const int E = in_sizes[1] / 2;
    const int G = out_size;
    const int Epad = (E + 63) & ~63;

    // ---- workspace layout ----
    float* ws    = (float*)d_ws;
    float* aggrA = ws;                                  // N*256 f32
    float* aggrB = aggrA + (size_t)N * 256;             // N*256 f32
    float* Wt    = aggrB + (size_t)N * 256;             // 256*256
    float* w4t   = Wt + 256 * 256;                      // 256*128
    unsigned short* ea_s  = (unsigned short*)(w4t + 256 * 128);   // Epad*32 bf16
    unsigned short* x_bf  = ea_s + (size_t)Epad * 32;   // N*64 bf16
    unsigned short* h_bf  = x_bf + (size_t)N * 64;      // N*256 bf16
    unsigned short* webf1 = h_bf + (size_t)N * 256;     // 64*32 bf16
    unsigned short* webf2 = webf1 + 64 * 32;            // 256*32
    unsigned short* webf3 = webf2 + 256 * 32;           // 256*32
    int* iws    = (int*)(webf3 + 256 * 32);
    int* ideg   = iws;                                  // N
    int* rowptr = ideg + N;                             // N+1
    int* cursor = rowptr + N + 1;                       // N
    int* eid_s  = cursor + N;                           // E
    int* esrc_s = eid_s + E;                            // Epad
    int* dst_s  = esrc_s + Epad;                        // Epad
    int* gcnt   = dst_s + Epad;                         // G
    int* gptr   = gcnt + G;                             // G+1

    const int nblk = (N + 31) / 32;

    // ---- CSR build + graph ranges + casts ----
    k_zero_i<<<64, 256, 0, stream>>>(ideg, N);
    k_zero_i<<<4, 256, 0, stream>>>(gcnt, G);
    k_hist<<<512, 256, 0, stream>>>(ei + E, ideg, E);
    k_hist<<<128, 256, 0, stream>>>(batch, gcnt, N);
    k_scan<<<1, 1024, 0, stream>>>(ideg, rowptr, N);
    k_scan<<<1, 1024, 0, stream>>>(gcnt, gptr, G);
    k_copy_i<<<64, 256, 0, stream>>>(rowptr, cursor, N);
    k_scatter<<<512, 256, 0, stream>>>(ei, E, cursor, eid_s, esrc_s, dst_s);
    k_pad_tail<<<1, 64, 0, stream>>>(esrc_s, dst_s, ea_s, E, Epad);
    k_permute_ea<<<2048, 256, 0, stream>>>(ea, eid_s, ea_s, E);
    k_cast_bf<<<512, 256, 0, stream>>>(x, x_bf, N * 64 / 4);
    k_cast_bf<<<2, 256, 0, stream>>>(we1, webf1, 64 * 32 / 4);
    k_cast_bf<<<8, 256, 0, stream>>>(we2, webf2, 256 * 32 / 4);
    k_cast_bf<<<8, 256, 0, stream>>>(we3, webf3, 256 * 32 / 4);
    k_copy_f4<<<512, 256, 0, stream>>>(x, aggrA, N * 64 / 4);   // layer-1 self term

    // ---- Layer 1 (D=64) ----
    k_edge_mfma<64><<<(E + 255) / 256, 256, 0, stream>>>(
        x_bf, ea_s, esrc_s, dst_s, webf1, be1, aggrA, E);
    k_transpose<<<(256 * 64 + 255) / 256, 256, 0, stream>>>(wn1, Wt, 256, 64);
    k_node<64, true><<<nblk, 256, 0, stream>>>(aggrA, Wt, bnb1, g1, b1, rm1, rv1,
                                               h_bf, aggrB, N);

    // ---- Layer 2 (D=256) ----
    k_edge_mfma<256><<<(E + 63) / 64, 256, 0, stream>>>(
        h_bf, ea_s, esrc_s, dst_s, webf2, be2, aggrB, E);
    k_transpose<<<(256 * 256 + 255) / 256, 256, 0, stream>>>(wn2, Wt, 256, 256);
    k_node<256, true><<<nblk, 256, 0, stream>>>(aggrB, Wt, bnb2, g2, b2, rm2, rv2,
                                                h_bf, aggrA, N);

    // ---- Layer 3 (D=256) ----
    k_edge_mfma<256><<<(E + 63) / 64, 256, 0, stream>>>(
        h_bf, ea_s, esrc_s, dst_s, webf3, be3, aggrA, E);
    k_transpose<<<(256 * 256 + 255) / 256, 256, 0, stream>>>(wn3, Wt, 256, 256);
    k_node<256, false><<<nblk, 256, 0, stream>>>(aggrA, Wt, bnb3, g3, b3, rm3, rv3,
                                                 h_bf, (float*)nullptr, N);

    // ---- Fused pool + head ----
    k_transpose<<<(128 * 256 + 255) / 256, 256, 0, stream>>>(w4, w4t, 128, 256);
    k_pool_head<<<G, 256, 0, stream>>>(h_bf, gptr, w4t, b4, w5, b5, (float*)d_out);
}

// Round 6
// 359.552 us; speedup vs baseline: 2.3078x; 1.1264x over previous
//
#include <hip/hip_runtime.h>
#include <hip/hip_bf16.h>
#include <math.h>

// ---------------------------------------------------------------------------
// GINE model: 3x (GINEConv + BN + ReLU) -> global mean pool -> MLP -> sigmoid
// Round 6: MFMA node GEMM (transposed-operand trick, LDS-free, barrier-free),
// bias folded into C-init, BN+ReLU epilogue with coalesced 8B/16B stores.
// Edge kernel unchanged from round 5.
// ---------------------------------------------------------------------------

typedef __attribute__((ext_vector_type(8))) short short8v;
typedef __attribute__((ext_vector_type(4))) float f32x4;
typedef __attribute__((ext_vector_type(4))) unsigned short us4;

static __device__ __forceinline__ float bf2f(unsigned short u) {
    union { unsigned int u32; float f; } c; c.u32 = ((unsigned int)u) << 16; return c.f;
}
static __device__ __forceinline__ unsigned short f2bf(float f) {
    union { float f; unsigned int u; } c; c.f = f;
    unsigned int lsb = (c.u >> 16) & 1u;
    c.u += 0x7fffu + lsb;
    return (unsigned short)(c.u >> 16);
}

__global__ void k_zero_i(int* __restrict__ p, int n) {
    int i = blockIdx.x * blockDim.x + threadIdx.x;
    int st = gridDim.x * blockDim.x;
    for (; i < n; i += st) p[i] = 0;
}

__global__ void k_copy_i(const int* __restrict__ s, int* __restrict__ d, int n) {
    int i = blockIdx.x * blockDim.x + threadIdx.x;
    int st = gridDim.x * blockDim.x;
    for (; i < n; i += st) d[i] = s[i];
}

__global__ void k_copy_f4(const float* __restrict__ s, float* __restrict__ d, int n4) {
    int i = blockIdx.x * blockDim.x + threadIdx.x;
    int st = gridDim.x * blockDim.x;
    const float4* s4 = (const float4*)s;
    float4* d4 = (float4*)d;
    for (; i < n4; i += st) d4[i] = s4[i];
}

__global__ void k_cast_bf(const float* __restrict__ s, unsigned short* __restrict__ d, int n4) {
    int i = blockIdx.x * blockDim.x + threadIdx.x;
    int st = gridDim.x * blockDim.x;
    for (; i < n4; i += st) {
        float4 t = ((const float4*)s)[i];
        us4 o; o.x = f2bf(t.x); o.y = f2bf(t.y); o.z = f2bf(t.z); o.w = f2bf(t.w);
        ((us4*)d)[i] = o;
    }
}

// transpose W[J][K] -> Wt[K][J]  (only used for the head's w4)
__global__ void k_transpose(const float* __restrict__ W, float* __restrict__ Wt, int J, int K) {
    int idx = blockIdx.x * blockDim.x + threadIdx.x;
    if (idx < J * K) {
        int j = idx / K, k = idx % K;
        Wt[k * J + j] = W[idx];
    }
}

__global__ void k_hist(const int* __restrict__ v, int* __restrict__ cnt, int n) {
    int i = blockIdx.x * blockDim.x + threadIdx.x;
    int st = gridDim.x * blockDim.x;
    for (; i < n; i += st) atomicAdd(&cnt[v[i]], 1);
}

// single-block exclusive scan, out has n+1 entries (out[n] = total)
__global__ __launch_bounds__(1024) void k_scan(const int* __restrict__ in,
                                               int* __restrict__ out, int n) {
    __shared__ int wsum[16];
    __shared__ int carry_s;
    const int tid = threadIdx.x;
    const int lane = tid & 63, wv = tid >> 6;
    if (tid == 0) carry_s = 0;
    __syncthreads();
    for (int base = 0; base < n; base += 1024) {
        int idx = base + tid;
        int v = (idx < n) ? in[idx] : 0;
        int s = v;
#pragma unroll
        for (int off = 1; off < 64; off <<= 1) {
            int t = __shfl_up(s, off);
            if (lane >= off) s += t;
        }
        if (lane == 63) wsum[wv] = s;
        __syncthreads();
        int woff = 0;
        for (int i = 0; i < wv; ++i) woff += wsum[i];
        int carry = carry_s;
        if (idx < n) out[idx] = carry + woff + s - v;
        __syncthreads();
        if (tid == 1023) carry_s = carry + woff + s;
        __syncthreads();
    }
    if (tid == 0) out[n] = carry_s;
}

// bucket edges by dst; record permuted src and dst
__global__ void k_scatter(const int* __restrict__ ei, int E, int* __restrict__ cursor,
                          int* __restrict__ eid_s, int* __restrict__ esrc_s,
                          int* __restrict__ dst_s) {
    int i = blockIdx.x * blockDim.x + threadIdx.x;
    int st = gridDim.x * blockDim.x;
    for (; i < E; i += st) {
        int d = ei[E + i];
        int pos = atomicAdd(&cursor[d], 1);
        eid_s[pos] = i;
        esrc_s[pos] = ei[i];
        dst_s[pos] = d;
    }
}

// pad tail rows [E, Epad): src=0, dst=-1, ea_s row = 0
__global__ void k_pad_tail(int* __restrict__ esrc_s, int* __restrict__ dst_s,
                           unsigned short* __restrict__ ea_s, int E, int Epad) {
    int i = E + threadIdx.x;
    if (i < Epad) {
        esrc_s[i] = 0;
        dst_s[i] = -1;
        for (int q = 0; q < 32; ++q) ea_s[(size_t)i * 32 + q] = 0;
    }
}

// ea_s[pos] = bf16(ea[eid_s[pos]]), CSR order; 8-elem granules
__global__ void k_permute_ea(const float* __restrict__ ea, const int* __restrict__ eid_s,
                             unsigned short* __restrict__ ea_s, int E) {
    int i = blockIdx.x * blockDim.x + threadIdx.x;
    int st = gridDim.x * blockDim.x;
    const int ng = E * 4;
    for (; i < ng; i += st) {
        int pos = i >> 2, q = i & 3;
        int e = eid_s[pos];
        const float4* sp = (const float4*)(ea + (size_t)e * 32 + q * 8);
        float4 a = sp[0], b = sp[1];
        us4 o0, o1;
        o0.x = f2bf(a.x); o0.y = f2bf(a.y); o0.z = f2bf(a.z); o0.w = f2bf(a.w);
        o1.x = f2bf(b.x); o1.y = f2bf(b.y); o1.z = f2bf(b.z); o1.w = f2bf(b.w);
        us4* dp = (us4*)(ea_s + (size_t)pos * 32 + q * 8);
        dp[0] = o0; dp[1] = o1;
    }
}

// ---------------------------------------------------------------------------
// Barrier-free edge kernel (round 5, unchanged).
// ---------------------------------------------------------------------------
template<int D>
__global__ __launch_bounds__(256) void k_edge_mfma(
    const unsigned short* __restrict__ hbf,
    const unsigned short* __restrict__ ea_s,
    const int* __restrict__ esrc_s,
    const int* __restrict__ dst_s,
    const unsigned short* __restrict__ webf,
    const float* __restrict__ be,
    float* __restrict__ aggr,
    int E)
{
    const int tid = threadIdx.x;
    const int lane = tid & 63;
    const int w = tid >> 6;
    const int l15 = lane & 15;
    const int lhi = lane >> 4;

    const int wavetile = (D == 256) ? (int)blockIdx.x : ((int)blockIdx.x * 4 + w);
    const int colbase  = (D == 256) ? (w * 64) : 0;
    const int e0 = wavetile * 64;
    if (e0 >= E) return;

    const int dstreg = dst_s[e0 + lane];

    int4 src4[4];
#pragma unroll
    for (int q = 0; q < 4; ++q)
        src4[q] = *(const int4*)(esrc_s + e0 + q * 16 + lhi * 4);

    short8v afr[4];
#pragma unroll
    for (int q = 0; q < 4; ++q)
        afr[q] = *(const short8v*)(ea_s + (size_t)(e0 + q * 16 + l15) * 32 + lhi * 8);

    short8v bfr[4]; float bias[4];
#pragma unroll
    for (int t = 0; t < 4; ++t) {
        int c = colbase + t * 16 + l15;
        bfr[t] = *(const short8v*)(webf + (size_t)c * 32 + lhi * 8);
        bias[t] = be[c];
    }

    unsigned short hv[4][4][4];
#pragma unroll
    for (int q = 0; q < 4; ++q) {
        const int sr[4] = {src4[q].x, src4[q].y, src4[q].z, src4[q].w};
#pragma unroll
        for (int i = 0; i < 4; ++i) {
            const unsigned short* hp = hbf + (size_t)sr[i] * D + colbase + l15;
#pragma unroll
            for (int t = 0; t < 4; ++t) hv[q][i][t] = hp[t * 16];
        }
    }

    f32x4 acc[4][4];
#pragma unroll
    for (int q = 0; q < 4; ++q)
#pragma unroll
        for (int t = 0; t < 4; ++t) {
            f32x4 ci; ci[0] = bias[t]; ci[1] = bias[t]; ci[2] = bias[t]; ci[3] = bias[t];
            acc[q][t] = __builtin_amdgcn_mfma_f32_16x16x32_bf16(afr[q], bfr[t], ci, 0, 0, 0);
        }

#pragma unroll
    for (int q = 0; q < 4; ++q)
#pragma unroll
        for (int t = 0; t < 4; ++t)
#pragma unroll
            for (int i = 0; i < 4; ++i)
                acc[q][t][i] = fmaxf(acc[q][t][i] + bf2f(hv[q][i][t]), 0.0f);

    int dprev = __shfl_up(dstreg, 1);
    bool bflag = (lane > 0) && (dstreg != dprev);
    unsigned long long bmask = __ballot(bflag);
    const int nseg = __builtin_popcountll(bmask) + 1;
    unsigned mlo = (unsigned)bmask, mhi = (unsigned)(bmask >> 32);
    const int segid_lane =
        __builtin_amdgcn_mbcnt_hi(mhi, __builtin_amdgcn_mbcnt_lo(mlo, 0)) + (bflag ? 1 : 0);

    int segid_qi[4][4];
#pragma unroll
    for (int q = 0; q < 4; ++q)
#pragma unroll
        for (int i = 0; i < 4; ++i) {
            int row = q * 16 + lhi * 4 + i;
            unsigned long long p = 1ull << row;
            segid_qi[q][i] = __builtin_popcountll(bmask & (p | (p - 1ull)));
        }

    for (int s = 0; s < nseg; ++s) {
        float a[4] = {0.0f, 0.0f, 0.0f, 0.0f};
#pragma unroll
        for (int q = 0; q < 4; ++q)
#pragma unroll
            for (int i = 0; i < 4; ++i) {
                bool tk = (segid_qi[q][i] == s);
#pragma unroll
                for (int t = 0; t < 4; ++t) a[t] += tk ? acc[q][t][i] : 0.0f;
            }
#pragma unroll
        for (int t = 0; t < 4; ++t) {
            a[t] += __shfl_xor(a[t], 16);
            a[t] += __shfl_xor(a[t], 32);
        }
        unsigned long long ms = __ballot(segid_lane == s);
        int fl = (int)__builtin_ctzll(ms);
        int dseg = __shfl(dstreg, fl);
        if (dseg >= 0 && lhi == 0) {
#pragma unroll
            for (int t = 0; t < 4; ++t)
                atomicAdd(aggr + (size_t)dseg * D + colbase + t * 16 + l15, a[t]);
        }
    }
}

// ---------------------------------------------------------------------------
// MFMA node GEMM + BN + ReLU. Computes D[n][m] = sum_k W[n][k]*A[m][k] with
// W as the row operand -> each lane's C fragment = 4 consecutive channels of
// one node row -> coalescible 8B bf16 + 16B f32 stores. LDS-free.
// Block: 256 thr = 4 waves; block covers 64 rows, wave w covers cols w*64.
// ---------------------------------------------------------------------------
template<int K, bool AW>
__global__ __launch_bounds__(256) void k_node_mfma(
    const float* __restrict__ A, const unsigned short* __restrict__ wnbf,
    const float* __restrict__ bnb, const float* __restrict__ g,
    const float* __restrict__ b, const float* __restrict__ rm,
    const float* __restrict__ rv, unsigned short* __restrict__ out,
    float* __restrict__ aggr_out, int N)
{
    const int tid = threadIdx.x;
    const int lane = tid & 63;
    const int w = tid >> 6;
    const int l15 = lane & 15;
    const int lhi = lane >> 4;
    const int row0 = blockIdx.x * 64;
    const int ncol0 = w * 64;

    // per-lane BN params for n = ncol0 + q*16 + lhi*4 + i; bias folds into C-init
    f32x4 scale[4], shift[4];
    f32x4 acc[4][4];
#pragma unroll
    for (int q = 0; q < 4; ++q) {
        int n0 = ncol0 + q * 16 + lhi * 4;
        float4 gg = *(const float4*)(g + n0);
        float4 rvv = *(const float4*)(rv + n0);
        float4 bb = *(const float4*)(b + n0);
        float4 rmm = *(const float4*)(rm + n0);
        float4 bn = *(const float4*)(bnb + n0);
        f32x4 sc, sh, ci;
        sc[0] = gg.x * rsqrtf(rvv.x + 1e-5f);
        sc[1] = gg.y * rsqrtf(rvv.y + 1e-5f);
        sc[2] = gg.z * rsqrtf(rvv.z + 1e-5f);
        sc[3] = gg.w * rsqrtf(rvv.w + 1e-5f);
        sh[0] = bb.x - rmm.x * sc[0];
        sh[1] = bb.y - rmm.y * sc[1];
        sh[2] = bb.z - rmm.z * sc[2];
        sh[3] = bb.w - rmm.w * sc[3];
        ci[0] = bn.x; ci[1] = bn.y; ci[2] = bn.z; ci[3] = bn.w;
        scale[q] = sc; shift[q] = sh;
#pragma unroll
        for (int r = 0; r < 4; ++r) acc[q][r] = ci;
    }

    for (int k0 = 0; k0 < K; k0 += 32) {
        short8v wfr[4];
#pragma unroll
        for (int q = 0; q < 4; ++q)
            wfr[q] = *(const short8v*)(wnbf + (size_t)(ncol0 + q * 16 + l15) * K + k0 + lhi * 8);
        short8v afr[4];
#pragma unroll
        for (int r = 0; r < 4; ++r) {
            const float* ap = A + (size_t)(row0 + r * 16 + l15) * K + k0 + lhi * 8;
            float4 a0 = ((const float4*)ap)[0];
            float4 a1 = ((const float4*)ap)[1];
            short8v t;
            t[0] = (short)f2bf(a0.x); t[1] = (short)f2bf(a0.y);
            t[2] = (short)f2bf(a0.z); t[3] = (short)f2bf(a0.w);
            t[4] = (short)f2bf(a1.x); t[5] = (short)f2bf(a1.y);
            t[6] = (short)f2bf(a1.z); t[7] = (short)f2bf(a1.w);
            afr[r] = t;
        }
#pragma unroll
        for (int q = 0; q < 4; ++q)
#pragma unroll
            for (int r = 0; r < 4; ++r)
                acc[q][r] = __builtin_amdgcn_mfma_f32_16x16x32_bf16(wfr[q], afr[r], acc[q][r], 0, 0, 0);
    }

#pragma unroll
    for (int r = 0; r < 4; ++r) {
        int m = row0 + r * 16 + l15;
        if (m < N) {
#pragma unroll
            for (int q = 0; q < 4; ++q) {
                int n0 = ncol0 + q * 16 + lhi * 4;
                f32x4 v = acc[q][r];
                f32x4 o;
#pragma unroll
                for (int i = 0; i < 4; ++i)
                    o[i] = fmaxf(v[i] * scale[q][i] + shift[q][i], 0.0f);
                us4 ob;
                ob.x = f2bf(o[0]); ob.y = f2bf(o[1]); ob.z = f2bf(o[2]); ob.w = f2bf(o[3]);
                *(us4*)(out + (size_t)m * 256 + n0) = ob;
                if (AW) *(f32x4*)(aggr_out + (size_t)m * 256 + n0) = o;
            }
        }
    }
}

// Fused global-mean-pool + MLP head (h in bf16).
__global__ __launch_bounds__(256) void k_pool_head(
    const unsigned short* __restrict__ h, const int* __restrict__ gptr,
    const float* __restrict__ w4t, const float* __restrict__ b4,
    const float* __restrict__ w5, const float* __restrict__ b5,
    float* __restrict__ out)
{
    __shared__ float pl[256];
    __shared__ float zs[128];
    const int g = blockIdx.x;
    const int tid = threadIdx.x;
    int beg = gptr[g], end = gptr[g + 1];
    float acc = 0.0f;
    for (int r = beg; r < end; ++r) acc += bf2f(h[(size_t)r * 256 + tid]);
    float cnt = (float)(end - beg);
    pl[tid] = acc / fmaxf(cnt, 1.0f);
    __syncthreads();
    if (tid < 128) {
        float a = b4[tid];
        for (int k = 0; k < 256; ++k) a += pl[k] * w4t[k * 128 + tid];
        zs[tid] = fmaxf(a, 0.0f);
    }
    __syncthreads();
    if (tid < 64) {
        float v = zs[tid] * w5[tid] + zs[tid + 64] * w5[tid + 64];
#pragma unroll
        for (int off = 32; off > 0; off >>= 1) v += __shfl_down(v, off);
        if (tid == 0) out[g] = 1.0f / (1.0f + expf(-(v + b5[0])));
    }
}

extern "C" void kernel_launch(void* const* d_in, const int* in_sizes, int n_in,
                              void* d_out, int out_size, void* d_ws, size_t ws_size,
                              hipStream_t stream)
{
    const float* x    = (const float*)d_in[0];
    const int*   ei   = (const int*)d_in[1];
    const float* ea   = (const float*)d_in[2];
    const int*   batch= (const int*)d_in[3];
    const float* we1  = (const float*)d_in[4];
    const float* be1  = (const float*)d_in[5];
    const float* wn1  = (const float*)d_in[6];
    const float* bnb1 = (const float*)d_in[7];
    const float* we2  = (const float*)d_in[8];
    const float* be2  = (const float*)d_in[9];
    const float* wn2  = (const float*)d_in[10];
    const float* bnb2 = (const float*)d_in[11];
    const float* we3  = (const float*)d_in[12];
    const float* be3  = (const float*)d_in[13];
    const float* wn3  = (const float*)d_in[14];
    const float* bnb3 = (const float*)d_in[15];
    const float* g1 = (const float*)d_in[16];
    const float* b1 = (const float*)d_in[17];
    const float* rm1= (const float*)d_in[18];
    const float* rv1= (const float*)d_in[19];
    const float* g2 = (const float*)d_in[20];
    const float* b2 = (const float*)d_in[21];
    const float* rm2= (const float*)d_in[22];
    const float* rv2= (const float*)d_in[23];
    const float* g3 = (const float*)d_in[24];
    const float* b3 = (const float*)d_in[25];
    const float* rm3= (const float*)d_in[26];
    const float* rv3= (const float*)d_in[27];
    const float* w4 = (const float*)d_in[28];
    const float* b4 = (const float*)d_in[29];
    const float* w5 = (const float*)d_in[30];
    const float* b5 = (const float*)d_in[31];

    const int N = in_sizes[0] / 64;
    const int E = in_sizes[1] / 2;
    const int G = out_size;
    const int Epad = (E + 63) & ~63;

    // ---- workspace layout ----
    float* ws    = (float*)d_ws;
    float* aggrA = ws;                                  // N*256 f32
    float* aggrB = aggrA + (size_t)N * 256;             // N*256 f32
    float* w4t   = aggrB + (size_t)N * 256;             // 256*128
    unsigned short* ea_s  = (unsigned short*)(w4t + 256 * 128);   // Epad*32 bf16
    unsigned short* x_bf  = ea_s + (size_t)Epad * 32;   // N*64 bf16
    unsigned short* h_bf  = x_bf + (size_t)N * 64;      // N*256 bf16
    unsigned short* webf1 = h_bf + (size_t)N * 256;     // 64*32 bf16
    unsigned short* webf2 = webf1 + 64 * 32;            // 256*32
    unsigned short* webf3 = webf2 + 256 * 32;           // 256*32
    unsigned short* wnbf1 = webf3 + 256 * 32;           // 256*64 bf16
    unsigned short* wnbf2 = wnbf1 + 256 * 64;           // 256*256
    unsigned short* wnbf3 = wnbf2 + 256 * 256;          // 256*256
    int* iws    = (int*)(wnbf3 + 256 * 256);
    int* ideg   = iws;                                  // N
    int* rowptr = ideg + N;                             // N+1
    int* cursor = rowptr + N + 1;                       // N
    int* eid_s  = cursor + N;                           // E
    int* esrc_s = eid_s + E;                            // Epad
    int* dst_s  = esrc_s + Epad;                        // Epad
    int* gcnt   = dst_s + Epad;                         // G
    int* gptr   = gcnt + G;                             // G+1

    const int nblk64 = (N + 63) / 64;

    // ---- CSR build + graph ranges + casts ----
    k_zero_i<<<64, 256, 0, stream>>>(ideg, N);
    k_zero_i<<<4, 256, 0, stream>>>(gcnt, G);
    k_hist<<<512, 256, 0, stream>>>(ei + E, ideg, E);
    k_hist<<<128, 256, 0, stream>>>(batch, gcnt, N);
    k_scan<<<1, 1024, 0, stream>>>(ideg, rowptr, N);
    k_scan<<<1, 1024, 0, stream>>>(gcnt, gptr, G);
    k_copy_i<<<64, 256, 0, stream>>>(rowptr, cursor, N);
    k_scatter<<<512, 256, 0, stream>>>(ei, E, cursor, eid_s, esrc_s, dst_s);
    k_pad_tail<<<1, 64, 0, stream>>>(esrc_s, dst_s, ea_s, E, Epad);
    k_permute_ea<<<2048, 256, 0, stream>>>(ea, eid_s, ea_s, E);
    k_cast_bf<<<512, 256, 0, stream>>>(x, x_bf, N * 64 / 4);
    k_cast_bf<<<2, 256, 0, stream>>>(we1, webf1, 64 * 32 / 4);
    k_cast_bf<<<8, 256, 0, stream>>>(we2, webf2, 256 * 32 / 4);
    k_cast_bf<<<8, 256, 0, stream>>>(we3, webf3, 256 * 32 / 4);
    k_cast_bf<<<16, 256, 0, stream>>>(wn1, wnbf1, 256 * 64 / 4);
    k_cast_bf<<<64, 256, 0, stream>>>(wn2, wnbf2, 256 * 256 / 4);
    k_cast_bf<<<64, 256, 0, stream>>>(wn3, wnbf3, 256 * 256 / 4);
    k_copy_f4<<<512, 256, 0, stream>>>(x, aggrA, N * 64 / 4);   // layer-1 self term

    // ---- Layer 1 (D=64) ----
    k_edge_mfma<64><<<(E + 255) / 256, 256, 0, stream>>>(
        x_bf, ea_s, esrc_s, dst_s, webf1, be1, aggrA, E);
    k_node_mfma<64, true><<<nblk64, 256, 0, stream>>>(aggrA, wnbf1, bnb1, g1, b1, rm1, rv1,
                                                      h_bf, aggrB, N);

    // ---- Layer 2 (D=256) ----
    k_edge_mfma<256><<<(E + 63) / 64, 256, 0, stream>>>(
        h_bf, ea_s, esrc_s, dst_s, webf2, be2, aggrB, E);
    k_node_mfma<256, true><<<nblk64, 256, 0, stream>>>(aggrB, wnbf2, bnb2, g2, b2, rm2, rv2,
                                                       h_bf, aggrA, N);

    // ---- Layer 3 (D=256) ----
    k_edge_mfma<256><<<(E + 63) / 64, 256, 0, stream>>>(
        h_bf, ea_s, esrc_s, dst_s, webf3, be3, aggrA, E);
    k_node_mfma<256, false><<<nblk64, 256, 0, stream>>>(aggrA, wnbf3, bnb3, g3, b3, rm3, rv3,
                                                        h_bf, (float*)nullptr, N);

    // ---- Fused pool + head ----
    k_transpose<<<(128 * 256 + 255) / 256, 256, 0, stream>>>(w4, w4t, 128, 256);
    k_pool_head<<<G, 256, 0, stream>>>(h_bf, gptr, w4t, b4, w5, b5, (float*)d_out);
}